// Round 8
// baseline (630.349 us; speedup 1.0000x reference)
//
#include <hip/hip_runtime.h>
#include <hip/hip_bf16.h>

#define V_NODES 100000
#define E_EDGES 600000
#define D_FEAT  128
#define VD      ((size_t)V_NODES * D_FEAT)
#define NREP    64
#define PART_SZ 12500   // V/8 for XCD-aligned adj partitioning
#define STRIDE  136     // LDS row stride (ushorts): 272B, 16B-aligned, bank-spread
#define SADJ_CAP 1024
#define REP_TOTAL (3 * NREP * 256)

typedef short bf16x8 __attribute__((ext_vector_type(8)));
typedef float f32x4  __attribute__((ext_vector_type(4)));

__device__ inline unsigned short f2bf(float f) {
    __hip_bfloat16 h = __float2bfloat16(f);
    unsigned short u;
    __builtin_memcpy(&u, &h, 2);
    return u;
}
__device__ inline float bfhi(unsigned int u) { return __uint_as_float(u & 0xffff0000u); }
__device__ inline float bflo(unsigned int u) { return __uint_as_float(u << 16); }

// ---------------------------------------------------------------------------
// Pack weights into bf16 MFMA B-fragment order (verified R4):
// wp[m][ ((s*8 + c)*64 + lane)*8 + j ] = W[c*16 + (lane&15)][s*32 + (lane>>4)*8 + j]
// ---------------------------------------------------------------------------
__global__ void pack_w_kernel(const float* __restrict__ W0,
                              const float* __restrict__ W1,
                              unsigned short* __restrict__ wp) {
    int m = blockIdx.y;            // 0..7
    int l = m >> 1, sel = m & 1;
    const float* W = (sel ? W1 : W0) + (size_t)l * 16384;
    int i = blockIdx.x * 256 + threadIdx.x;   // 0..16383
    int j    = i & 7;
    int lane = (i >> 3) & 63;
    int c    = (i >> 9) & 7;
    int s    = i >> 12;
    int n0 = lane & 15, q = lane >> 4;
    float v = W[(c * 16 + n0) * 128 + s * 32 + q * 8 + j];
    wp[(size_t)m * 16384 + i] = f2bf(v);
}

// ---------------------------------------------------------------------------
// Fused GEMM. A = relu(norm(x) [+res]) built inline as bf16 fragments.
// Single LDS staging buffer used twice (y then h) -> 18.5 KB LDS, high occ.
// ---------------------------------------------------------------------------
__global__ __launch_bounds__(256, 6) void gemm_fused_kernel(
    const float* __restrict__ xf, const unsigned short* __restrict__ xh,
    const float* __restrict__ stats,   // null => no BN (layer 0)
    const float* __restrict__ gamma, const float* __restrict__ beta,
    const float* __restrict__ res,     // null unless layer 3
    const unsigned short* __restrict__ wp0, const float* __restrict__ bias0,
    float* __restrict__ outf, unsigned short* __restrict__ outh,
    const unsigned short* __restrict__ wp1, const float* __restrict__ bias1,
    unsigned short* __restrict__ yb,
    int V) {
    __shared__ float lsc[128], lsh[128];
    __shared__ unsigned short st[64 * STRIDE];
    const int t = threadIdx.x;
    if (stats) {
        if (t < 128) {
            float inv = 1.0f / (float)V;
            float mu  = stats[t] * inv;
            float var = stats[128 + t] * inv - mu * mu;
            float sc  = gamma[t] * rsqrtf(var + 1e-5f);
            lsc[t] = sc;
            lsh[t] = beta[t] - mu * sc;
        }
        __syncthreads();
    }

    const int wave = t >> 6;
    const int lane = t & 63;
    const int n0   = lane & 15;
    const int q    = lane >> 4;

    const int arow = blockIdx.x * 64 + wave * 16 + n0;
    bf16x8 a[4];
    {
        bf16x8 z = {0, 0, 0, 0, 0, 0, 0, 0};
#pragma unroll
        for (int s = 0; s < 4; ++s) a[s] = z;
    }
    if (arow < V) {
        const float* rr = res ? res + (size_t)arow * 128 : nullptr;
#pragma unroll
        for (int s = 0; s < 4; ++s) {
            int base = s * 32 + q * 8;
            float v[8];
            if (xh) {
                uint4 p = *reinterpret_cast<const uint4*>(xh + (size_t)arow * 128 + base);
                v[0] = bflo(p.x); v[1] = bfhi(p.x);
                v[2] = bflo(p.y); v[3] = bfhi(p.y);
                v[4] = bflo(p.z); v[5] = bfhi(p.z);
                v[6] = bflo(p.w); v[7] = bfhi(p.w);
            } else {
                const float* xr = xf + (size_t)arow * 128 + base;
                float4 p0 = *reinterpret_cast<const float4*>(xr);
                float4 p1 = *reinterpret_cast<const float4*>(xr + 4);
                v[0] = p0.x; v[1] = p0.y; v[2] = p0.z; v[3] = p0.w;
                v[4] = p1.x; v[5] = p1.y; v[6] = p1.z; v[7] = p1.w;
            }
            if (stats) {
#pragma unroll
                for (int j = 0; j < 8; ++j)
                    v[j] = v[j] * lsc[base + j] + lsh[base + j];
                if (rr) {
                    float4 r0 = *reinterpret_cast<const float4*>(rr + base);
                    float4 r1 = *reinterpret_cast<const float4*>(rr + base + 4);
                    v[0] += r0.x; v[1] += r0.y; v[2] += r0.z; v[3] += r0.w;
                    v[4] += r1.x; v[5] += r1.y; v[6] += r1.z; v[7] += r1.w;
                }
#pragma unroll
                for (int j = 0; j < 8; ++j) v[j] = fmaxf(v[j], 0.f);
            }
            bf16x8 af;
#pragma unroll
            for (int j = 0; j < 8; ++j) af[j] = (short)f2bf(v[j]);
            a[s] = af;
        }
    }

    f32x4 acc0[8], acc1[8];
    f32x4 z4 = {0.f, 0.f, 0.f, 0.f};
#pragma unroll
    for (int c = 0; c < 8; ++c) { acc0[c] = z4; acc1[c] = z4; }

#pragma unroll
    for (int c = 0; c < 8; ++c) {
#pragma unroll
        for (int s = 0; s < 4; ++s) {
            size_t off = ((size_t)((s * 8 + c) * 64 + lane)) * 8;
            bf16x8 b0f = *reinterpret_cast<const bf16x8*>(wp0 + off);
            bf16x8 b1f = *reinterpret_cast<const bf16x8*>(wp1 + off);
            acc0[c] = __builtin_amdgcn_mfma_f32_16x16x32_bf16(a[s], b0f, acc0[c], 0, 0, 0);
            acc1[c] = __builtin_amdgcn_mfma_f32_16x16x32_bf16(a[s], b1f, acc1[c], 0, 0, 0);
        }
    }

    // ---- Stage & write y ----  C/D layout: col = lane&15, row = q*4 + reg
    const int lrow0 = wave * 16 + q * 4;
#pragma unroll
    for (int c = 0; c < 8; ++c) {
        float bv1 = bias1[c * 16 + n0];
#pragma unroll
        for (int r = 0; r < 4; ++r)
            st[(lrow0 + r) * STRIDE + c * 16 + n0] = f2bf(acc1[c][r] + bv1);
    }
    __syncthreads();
#pragma unroll
    for (int it = 0; it < 4; ++it) {
        int chunk = it * 256 + t;
        int lrow = chunk >> 4, c8 = chunk & 15;
        int grow = blockIdx.x * 64 + lrow;
        if (grow < V) {
            uint4 hy = *reinterpret_cast<const uint4*>(&st[lrow * STRIDE + c8 * 8]);
            *reinterpret_cast<uint4*>(&yb[(size_t)grow * 128 + c8 * 8]) = hy;
        }
    }
    __syncthreads();

    // ---- Stage & write h ---- (overwrites this block's own x rows; A-frags
    // were consumed before the barriers above, so in-place is safe.)
#pragma unroll
    for (int c = 0; c < 8; ++c) {
        float bv0 = bias0[c * 16 + n0];
#pragma unroll
        for (int r = 0; r < 4; ++r)
            st[(lrow0 + r) * STRIDE + c * 16 + n0] = f2bf(acc0[c][r] + bv0);
    }
    __syncthreads();
#pragma unroll
    for (int it = 0; it < 4; ++it) {
        int chunk = it * 256 + t;
        int lrow = chunk >> 4, c8 = chunk & 15;
        int grow = blockIdx.x * 64 + lrow;
        if (grow < V) {
            size_t gidx = (size_t)grow * 128 + c8 * 8;
            uint4 hh = *reinterpret_cast<const uint4*>(&st[lrow * STRIDE + c8 * 8]);
            if (outh) {
                *reinterpret_cast<uint4*>(&outh[gidx]) = hh;
            } else {
                float4 f0 = make_float4(bflo(hh.x), bfhi(hh.x), bflo(hh.y), bfhi(hh.y));
                float4 f1 = make_float4(bflo(hh.z), bfhi(hh.z), bflo(hh.w), bfhi(hh.w));
                *reinterpret_cast<float4*>(&outf[gidx])     = f0;
                *reinterpret_cast<float4*>(&outf[gidx + 4]) = f1;
            }
        }
    }
}

// ---------------------------------------------------------------------------
// CSR construction — multi-block scan
// ---------------------------------------------------------------------------
__global__ void zero_both_kernel(int* __restrict__ deg, float* __restrict__ rep) {
    int i = blockIdx.x * 256 + threadIdx.x;
    if (i < V_NODES) deg[i] = 0;
    if (i < REP_TOTAL) rep[i] = 0.f;
}

__global__ __launch_bounds__(256) void degree_kernel(
    const int* __restrict__ edges, int* __restrict__ deg, int E) {
    int i = blockIdx.x * 256 + threadIdx.x;
    if (i >= E) return;
    atomicAdd(&deg[edges[2 * i]], 1);
    atomicAdd(&deg[edges[2 * i + 1]], 1);
}

__global__ __launch_bounds__(256) void block_sum_kernel(
    const int* __restrict__ deg, int* __restrict__ bsums, int V) {
    __shared__ int sh[256];
    int i = blockIdx.x * 256 + threadIdx.x;
    sh[threadIdx.x] = (i < V) ? deg[i] : 0;
    __syncthreads();
    for (int off = 128; off > 0; off >>= 1) {
        if (threadIdx.x < off) sh[threadIdx.x] += sh[threadIdx.x + off];
        __syncthreads();
    }
    if (threadIdx.x == 0) bsums[blockIdx.x] = sh[0];
}

__global__ __launch_bounds__(512) void scan_bsums_kernel(int* __restrict__ bsums, int nb) {
    __shared__ int sh[512];
    int t = threadIdx.x;
    int v = (t < nb) ? bsums[t] : 0;
    sh[t] = v;
    __syncthreads();
    for (int off = 1; off < 512; off <<= 1) {
        int add = (t >= off) ? sh[t - off] : 0;
        __syncthreads();
        sh[t] += add;
        __syncthreads();
    }
    if (t < nb) bsums[t] = sh[t] - v;   // exclusive
}

__global__ __launch_bounds__(256) void offsets_kernel(
    const int* __restrict__ deg, const int* __restrict__ bsums,
    int* __restrict__ offsets, int* __restrict__ cursor, int V) {
    __shared__ int sh[256];
    int t = threadIdx.x;
    int i = blockIdx.x * 256 + t;
    int v = (i < V) ? deg[i] : 0;
    sh[t] = v;
    __syncthreads();
    for (int off = 1; off < 256; off <<= 1) {
        int add = (t >= off) ? sh[t - off] : 0;
        __syncthreads();
        sh[t] += add;
        __syncthreads();
    }
    int excl = sh[t] - v + bsums[blockIdx.x];
    if (i < V) { offsets[i] = excl; cursor[i] = excl; }
    if (i == V - 1) offsets[V] = excl + v;
}

// XCD-partitioned adj fill (verified R6: kills partial-line writeback storm).
__global__ __launch_bounds__(256) void fill_adj_kernel(
    const int* __restrict__ edges, int* __restrict__ cursor,
    int* __restrict__ adj, int E) {
    int part = blockIdx.x & 7;
    int i = (blockIdx.x >> 3) * 256 + threadIdx.x;
    if (i >= E) return;
    int a = edges[2 * i], b = edges[2 * i + 1];
    if (a / PART_SZ == part) { int pa = atomicAdd(&cursor[a], 1); adj[pa] = b; }
    if (b / PART_SZ == part) { int pb = atomicAdd(&cursor[b], 1); adj[pb] = a; }
}

// ---------------------------------------------------------------------------
// Gather + fused BN stats. 16 lanes/node (8 bf16 cols/lane).
// Block's 16-node CSR segment prefetched into LDS; neighbor loop unrolled 4x.
// ---------------------------------------------------------------------------
__global__ __launch_bounds__(256) void gather_stats_kernel(
    const unsigned short* __restrict__ yb, const int* __restrict__ offsets,
    const int* __restrict__ adj,
    float* __restrict__ outf, unsigned short* __restrict__ outh,
    float* __restrict__ rep, int V) {
    __shared__ int sadj[SADJ_CAP];
    __shared__ float part[4][16][16];
    const int t    = threadIdx.x;
    const int nodeBase = blockIdx.x * 16;
    const int node = nodeBase + (t >> 4);
    const int l8   = t & 15;                 // cols l8*8 .. +7

    const int segStart = offsets[min(nodeBase, V)];
    const int segEnd   = offsets[min(nodeBase + 16, V)];
    const int segLen   = segEnd - segStart;
    const bool inLds   = (segLen <= SADJ_CAP);
    if (inLds)
        for (int j = t; j < segLen; j += 256) sadj[j] = adj[segStart + j];
    __syncthreads();

    float o[8];
#pragma unroll
    for (int k = 0; k < 8; ++k) o[k] = 0.f;

    if (node < V) {
        int start = offsets[node] - segStart, end = offsets[node + 1] - segStart;
        float acc[8];
#pragma unroll
        for (int k = 0; k < 8; ++k) acc[k] = 0.f;

        const int* src = inLds ? sadj : adj + segStart;
        int i = start;
        for (; i + 3 < end; i += 4) {
            int u0 = src[i], u1 = src[i + 1], u2 = src[i + 2], u3 = src[i + 3];
            uint4 p0 = *reinterpret_cast<const uint4*>(yb + (size_t)u0 * 128 + l8 * 8);
            uint4 p1 = *reinterpret_cast<const uint4*>(yb + (size_t)u1 * 128 + l8 * 8);
            uint4 p2 = *reinterpret_cast<const uint4*>(yb + (size_t)u2 * 128 + l8 * 8);
            uint4 p3 = *reinterpret_cast<const uint4*>(yb + (size_t)u3 * 128 + l8 * 8);
            acc[0] += bflo(p0.x); acc[1] += bfhi(p0.x);
            acc[2] += bflo(p0.y); acc[3] += bfhi(p0.y);
            acc[4] += bflo(p0.z); acc[5] += bfhi(p0.z);
            acc[6] += bflo(p0.w); acc[7] += bfhi(p0.w);
            acc[0] += bflo(p1.x); acc[1] += bfhi(p1.x);
            acc[2] += bflo(p1.y); acc[3] += bfhi(p1.y);
            acc[4] += bflo(p1.z); acc[5] += bfhi(p1.z);
            acc[6] += bflo(p1.w); acc[7] += bfhi(p1.w);
            acc[0] += bflo(p2.x); acc[1] += bfhi(p2.x);
            acc[2] += bflo(p2.y); acc[3] += bfhi(p2.y);
            acc[4] += bflo(p2.z); acc[5] += bfhi(p2.z);
            acc[6] += bflo(p2.w); acc[7] += bfhi(p2.w);
            acc[0] += bflo(p3.x); acc[1] += bfhi(p3.x);
            acc[2] += bflo(p3.y); acc[3] += bfhi(p3.y);
            acc[4] += bflo(p3.z); acc[5] += bfhi(p3.z);
            acc[6] += bflo(p3.w); acc[7] += bfhi(p3.w);
        }
        for (; i < end; ++i) {
            int u0 = src[i];
            uint4 p0 = *reinterpret_cast<const uint4*>(yb + (size_t)u0 * 128 + l8 * 8);
            acc[0] += bflo(p0.x); acc[1] += bfhi(p0.x);
            acc[2] += bflo(p0.y); acc[3] += bfhi(p0.y);
            acc[4] += bflo(p0.z); acc[5] += bfhi(p0.z);
            acc[6] += bflo(p0.w); acc[7] += bfhi(p0.w);
        }

        if (outh) {
            unsigned short* op = outh + (size_t)node * 128 + l8 * 8;
            uint4 h = *reinterpret_cast<const uint4*>(op);
            o[0] = bflo(h.x) + acc[0]; o[1] = bfhi(h.x) + acc[1];
            o[2] = bflo(h.y) + acc[2]; o[3] = bfhi(h.y) + acc[3];
            o[4] = bflo(h.z) + acc[4]; o[5] = bfhi(h.z) + acc[5];
            o[6] = bflo(h.w) + acc[6]; o[7] = bfhi(h.w) + acc[7];
            uint4 hn;
            hn.x = (unsigned)f2bf(o[0]) | ((unsigned)f2bf(o[1]) << 16);
            hn.y = (unsigned)f2bf(o[2]) | ((unsigned)f2bf(o[3]) << 16);
            hn.z = (unsigned)f2bf(o[4]) | ((unsigned)f2bf(o[5]) << 16);
            hn.w = (unsigned)f2bf(o[6]) | ((unsigned)f2bf(o[7]) << 16);
            *reinterpret_cast<uint4*>(op) = hn;
        } else {
            float* op = outf + (size_t)node * 128 + l8 * 8;
            float4 o0 = reinterpret_cast<const float4*>(op)[0];
            float4 o1 = reinterpret_cast<const float4*>(op)[1];
            o[0] = o0.x + acc[0]; o[1] = o0.y + acc[1];
            o[2] = o0.z + acc[2]; o[3] = o0.w + acc[3];
            o[4] = o1.x + acc[4]; o[5] = o1.y + acc[5];
            o[6] = o1.z + acc[6]; o[7] = o1.w + acc[7];
            reinterpret_cast<float4*>(op)[0] = make_float4(o[0], o[1], o[2], o[3]);
            reinterpret_cast<float4*>(op)[1] = make_float4(o[4], o[5], o[6], o[7]);
        }
    }

    if (rep) {
        const int lane = t & 63, wave = t >> 6;
        float s[8], qq[8];
#pragma unroll
        for (int k = 0; k < 8; ++k) { s[k] = o[k]; qq[k] = o[k] * o[k]; }
#pragma unroll
        for (int k = 0; k < 8; ++k) {
            s[k]  += __shfl_xor(s[k], 16);  qq[k] += __shfl_xor(qq[k], 16);
            s[k]  += __shfl_xor(s[k], 32);  qq[k] += __shfl_xor(qq[k], 32);
        }
        if (lane < 16) {
#pragma unroll
            for (int k = 0; k < 8; ++k) {
                part[wave][lane][k]     = s[k];
                part[wave][lane][8 + k] = qq[k];
            }
        }
        __syncthreads();
        int l8b = t >> 4, slot = t & 15;
        float tot = part[0][l8b][slot] + part[1][l8b][slot] +
                    part[2][l8b][slot] + part[3][l8b][slot];
        int col = l8b * 8 + (slot & 7);
        float* dst = rep + (size_t)(blockIdx.x & (NREP - 1)) * 256 +
                     (slot < 8 ? col : 128 + col);
        atomicAdd(dst, tot);
    }
}

// ---------------------------------------------------------------------------
__global__ void reduce_stats_kernel(const float* __restrict__ rep,
                                    float* __restrict__ sf) {
    int t = threadIdx.x;   // 256
    float s = 0.f;
#pragma unroll 8
    for (int r = 0; r < NREP; ++r) s += rep[r * 256 + t];
    sf[t] = s;
}

// ---------------------------------------------------------------------------
extern "C" void kernel_launch(void* const* d_in, const int* in_sizes, int n_in,
                              void* d_out, int out_size, void* d_ws, size_t ws_size,
                              hipStream_t stream) {
    const float* feat  = (const float*)d_in[0];
    const int*   edges = (const int*)d_in[1];
    const float* W0    = (const float*)d_in[2];
    const float* b0    = (const float*)d_in[3];
    const float* W1    = (const float*)d_in[4];
    const float* b1    = (const float*)d_in[5];
    const float* gamma = (const float*)d_in[6];
    const float* beta  = (const float*)d_in[7];
    float* out = (float*)d_out;

    unsigned short* hb = (unsigned short*)d_ws;   // [V,128] bf16 h0/activations
    unsigned short* yb = hb + VD;                 // [V,128] bf16 messages
    unsigned short* wp = yb + VD;                 // 8 x 16384 bf16 packed weights
    float* rep     = (float*)(wp + 8 * 16384);    // 3 x NREP x 256
    float* sf      = rep + REP_TOTAL;             // 3 x 256 final stats
    int*   deg     = (int*)(sf + 768);            // V
    int*   offsets = deg + V_NODES;               // V+1
    int*   cursor  = offsets + V_NODES + 1;       // V
    int*   bsums   = cursor + V_NODES;            // <=512
    int*   adj     = bsums + 512;                 // 2E

    const int V = V_NODES, E = E_EDGES;
    const int gemm_blocks = (V + 63) / 64;       // 1563
    const int gath_blocks = (V + 15) / 16;       // 6250
    const int vblocks     = (V + 255) / 256;     // 391
    const int eblocks     = (E + 255) / 256;     // 2344

    // Per-launch prep
    pack_w_kernel<<<dim3(64, 8), 256, 0, stream>>>(W0, W1, wp);
    zero_both_kernel<<<vblocks, 256, 0, stream>>>(deg, rep);
    degree_kernel<<<eblocks, 256, 0, stream>>>(edges, deg, E);
    block_sum_kernel<<<vblocks, 256, 0, stream>>>(deg, bsums, V);
    scan_bsums_kernel<<<1, 512, 0, stream>>>(bsums, vblocks);
    offsets_kernel<<<vblocks, 256, 0, stream>>>(deg, bsums, offsets, cursor, V);
    fill_adj_kernel<<<8 * eblocks, 256, 0, stream>>>(edges, cursor, adj, E);

    for (int l = 0; l < 4; ++l) {
        const float*          xf    = (l == 0) ? feat : nullptr;
        const unsigned short* xh    = (l == 0) ? nullptr : hb;
        const float*          stats = (l == 0) ? nullptr : sf + (size_t)(l - 1) * 256;
        const float*          gam   = (l == 0) ? nullptr : gamma + (l - 1) * 128;
        const float*          bet   = (l == 0) ? nullptr : beta + (l - 1) * 128;
        const float*          res   = (l == 3) ? feat : nullptr;
        float*          outf = (l == 3) ? out : nullptr;
        unsigned short* outh = (l == 3) ? nullptr : hb;

        gemm_fused_kernel<<<gemm_blocks, 256, 0, stream>>>(
            xf, xh, stats, gam, bet, res,
            wp + (size_t)(2 * l) * 16384,     b0 + l * 128, outf, outh,
            wp + (size_t)(2 * l + 1) * 16384, b1 + l * 128, yb,
            V);

        float* rep_l = (l < 3) ? rep + (size_t)l * NREP * 256 : nullptr;
        gather_stats_kernel<<<gath_blocks, 256, 0, stream>>>(
            yb, offsets, adj, outf, outh, rep_l, V);
        if (l < 3)
            reduce_stats_kernel<<<1, 256, 0, stream>>>(rep_l, sf + (size_t)l * 256);
    }
}